// Round 19
// baseline (812.776 us; speedup 1.0000x reference)
//
#include <hip/hip_runtime.h>
#include <hip/hip_bf16.h>
#include <math.h>

#define BB 2
#define TT 1024
#define DD 1024
#define NH 16
#define KVHN 4
#define NL 4
#define II 2730
#define IIP 2816
#define NTOK (BB * TT)
#define QKVD 1536
#define KSTR 72

typedef __hip_bfloat16 bf16;
typedef __attribute__((ext_vector_type(8))) short bf16x8;
typedef __attribute__((ext_vector_type(4))) float f32x4;

#define GLOAD16(gp, lp)                                                        \
    __builtin_amdgcn_global_load_lds(                                          \
        (const __attribute__((address_space(1))) unsigned int*)(gp),           \
        (__attribute__((address_space(3))) unsigned int*)(lp), 16, 0, 0)

__device__ inline float b2f(unsigned short u) {
    union { unsigned int i; float f; } v;
    v.i = (unsigned int)u << 16;
    return v.f;
}
__device__ inline unsigned short f2b(float f) {
    __hip_bfloat16 b = __float2bfloat16(f);
    return *(unsigned short*)&b;
}

// ---------------- rope sin/cos table ----------------
__global__ void rope_table_k(float* __restrict__ st, float* __restrict__ ct) {
    int i = blockIdx.x * 256 + threadIdx.x;
    if (i >= TT * 64) return;
    int t = i >> 6, d = i & 63;
    float freq = powf(10000.0f, (float)(d & 31) / 32.0f);
    float ang = (float)t / freq;
    st[i] = sinf(ang);
    ct[i] = cosf(ang);
}

// ---------------- embedding gather (fp32 residual) ----------------
__global__ __launch_bounds__(256) void embed_k(const int* __restrict__ idx,
                                               const float* __restrict__ wte,
                                               float* __restrict__ x) {
    int row = blockIdx.x;
    int tok = idx[row];
    const float4* src = (const float4*)(wte + (size_t)tok * DD);
    float4* dst = (float4*)(x + (size_t)row * DD);
    dst[threadIdx.x] = src[threadIdx.x];
}

// ---------------- rmsnorm: fp32 in -> bf16 out ----------------
__global__ __launch_bounds__(256) void rmsnorm_k(const float* __restrict__ x,
                                                 const float* __restrict__ w,
                                                 bf16* __restrict__ o) {
    int row = blockIdx.x;
    float4 v = ((const float4*)(x + (size_t)row * DD))[threadIdx.x];
    float s = v.x * v.x + v.y * v.y + v.z * v.z + v.w * v.w;
#pragma unroll
    for (int off = 32; off > 0; off >>= 1) s += __shfl_down(s, off);
    __shared__ float red[4];
    if ((threadIdx.x & 63) == 0) red[threadIdx.x >> 6] = s;
    __syncthreads();
    float tot = red[0] + red[1] + red[2] + red[3];
    float r = rsqrtf(tot * (1.0f / DD) + 1e-6f);
    float4 wv = ((const float4*)w)[threadIdx.x];
    size_t base = (size_t)row * DD + threadIdx.x * 4;
    ushort4 ov;
    ov.x = f2b(v.x * r * wv.x);
    ov.y = f2b(v.y * r * wv.y);
    ov.z = f2b(v.z * r * wv.z);
    ov.w = f2b(v.w * r * wv.w);
    *(ushort4*)(o + base) = ov;
}

// ---------------- MFMA flash attention (bf16, causal, GQA h%4) ------------
// 1D grid of 512, complementary qt pairing (uniform 17 KV-tiles per CU).
__global__ __launch_bounds__(256) void attn_mfma_k(const bf16* __restrict__ qp,
                                                   const bf16* __restrict__ kp,
                                                   const bf16* __restrict__ vt,
                                                   bf16* __restrict__ y) {
    int i = blockIdx.x;
    int b = i >> 8;
    int base = i & 255;
    int h = base >> 4;
    int q4 = base & 15;
    int qt = b ? (15 - q4) : q4;
    int kvh = h & (KVHN - 1);

    __shared__ __align__(16) bf16 Ks[64][KSTR];
    __shared__ __align__(16) bf16 Vt[64][KSTR];
    __shared__ __align__(16) bf16 Ps[4][16][KSTR];

    int tid = threadIdx.x;
    int lane = tid & 63;
    int w = tid >> 6;
    int qi = lane & 15;
    int g = lane >> 4;

    const bf16* qbase = qp + (((size_t)(b * NH + h) * TT + qt * 64 + w * 16 + qi) * 64);
    bf16x8 qf0 = *(const bf16x8*)(qbase + g * 8);
    bf16x8 qf1 = *(const bf16x8*)(qbase + 32 + g * 8);

    const bf16* kg = kp + ((size_t)(b * KVHN + kvh) * TT) * 64;
    const bf16* vg = vt + ((size_t)(b * KVHN + kvh) * 64) * TT;

    int c0 = tid, c1 = tid + 256;
    auto ldK = [&](int kt, int c) {
        return *(const bf16x8*)(kg + (size_t)(kt * 64 + (c >> 3)) * 64 + (c & 7) * 8);
    };
    auto ldV = [&](int kt, int c) {
        return *(const bf16x8*)(vg + (size_t)(c >> 3) * TT + kt * 64 + (c & 7) * 8);
    };

    f32x4 oacc[4] = {};
    float m = -INFINITY, l = 0.0f;
    int qglob = qt * 64 + w * 16 + qi;

    bf16x8 rk0 = ldK(0, c0), rk1 = ldK(0, c1);
    bf16x8 rv0 = ldV(0, c0), rv1 = ldV(0, c1);

    for (int kt = 0; kt <= qt; ++kt) {
        __syncthreads();
        *(bf16x8*)(&Ks[c0 >> 3][(c0 & 7) * 8]) = rk0;
        *(bf16x8*)(&Ks[c1 >> 3][(c1 & 7) * 8]) = rk1;
        *(bf16x8*)(&Vt[c0 >> 3][(c0 & 7) * 8]) = rv0;
        *(bf16x8*)(&Vt[c1 >> 3][(c1 & 7) * 8]) = rv1;
        __syncthreads();

        if (kt < qt) {
            rk0 = ldK(kt + 1, c0); rk1 = ldK(kt + 1, c1);
            rv0 = ldV(kt + 1, c0); rv1 = ldV(kt + 1, c1);
        }

        f32x4 sacc[4] = {};
#pragma unroll
        for (int stt = 0; stt < 4; ++stt) {
            bf16x8 kf0 = *(const bf16x8*)(&Ks[stt * 16 + qi][g * 8]);
            bf16x8 kf1 = *(const bf16x8*)(&Ks[stt * 16 + qi][32 + g * 8]);
            sacc[stt] = __builtin_amdgcn_mfma_f32_16x16x32_bf16(kf0, qf0, sacc[stt], 0, 0, 0);
            sacc[stt] = __builtin_amdgcn_mfma_f32_16x16x32_bf16(kf1, qf1, sacc[stt], 0, 0, 0);
        }

        if (kt == qt) {
#pragma unroll
            for (int stt = 0; stt < 4; ++stt)
#pragma unroll
                for (int r = 0; r < 4; ++r) {
                    int kgl = kt * 64 + stt * 16 + g * 4 + r;
                    if (kgl > qglob) sacc[stt][r] = -INFINITY;
                }
        }

        float tmax = -INFINITY;
#pragma unroll
        for (int stt = 0; stt < 4; ++stt)
#pragma unroll
            for (int r = 0; r < 4; ++r) tmax = fmaxf(tmax, sacc[stt][r]);
        tmax = fmaxf(tmax, __shfl_xor(tmax, 16));
        tmax = fmaxf(tmax, __shfl_xor(tmax, 32));
        float mnew = fmaxf(m, tmax);
        float scale = __expf(m - mnew);
        float psum = 0.0f;
#pragma unroll
        for (int stt = 0; stt < 4; ++stt) {
            bf16 pb[4];
#pragma unroll
            for (int r = 0; r < 4; ++r) {
                float p = __expf(sacc[stt][r] - mnew);
                psum += p;
                pb[r] = __float2bfloat16(p);
            }
            *(uint2*)(&Ps[w][qi][stt * 16 + g * 4]) = *(uint2*)pb;
        }
        psum += __shfl_xor(psum, 16);
        psum += __shfl_xor(psum, 32);
        l = l * scale + psum;
        m = mnew;

        float sc0 = __shfl(scale, g * 4 + 0);
        float sc1 = __shfl(scale, g * 4 + 1);
        float sc2 = __shfl(scale, g * 4 + 2);
        float sc3 = __shfl(scale, g * 4 + 3);
#pragma unroll
        for (int dt = 0; dt < 4; ++dt) {
            oacc[dt][0] *= sc0; oacc[dt][1] *= sc1;
            oacc[dt][2] *= sc2; oacc[dt][3] *= sc3;
        }

#pragma unroll
        for (int kc = 0; kc < 2; ++kc) {
            bf16x8 pa = *(const bf16x8*)(&Ps[w][qi][kc * 32 + g * 8]);
#pragma unroll
            for (int dt = 0; dt < 4; ++dt) {
                bf16x8 vb2 = *(const bf16x8*)(&Vt[dt * 16 + qi][kc * 32 + g * 8]);
                oacc[dt] = __builtin_amdgcn_mfma_f32_16x16x32_bf16(pa, vb2, oacc[dt], 0, 0, 0);
            }
        }
    }

    float linv = 1.0f / l;
    float li0 = __shfl(linv, g * 4 + 0);
    float li1 = __shfl(linv, g * 4 + 1);
    float li2 = __shfl(linv, g * 4 + 2);
    float li3 = __shfl(linv, g * 4 + 3);
#pragma unroll
    for (int dt = 0; dt < 4; ++dt) {
        int dcol = h * 64 + dt * 16 + qi;
        size_t r0 = (size_t)(b * TT + qt * 64 + w * 16 + g * 4) * DD + dcol;
        y[r0 + 0 * DD] = __float2bfloat16(oacc[dt][0] * li0);
        y[r0 + 1 * DD] = __float2bfloat16(oacc[dt][1] * li1);
        y[r0 + 2 * DD] = __float2bfloat16(oacc[dt][2] * li2);
        y[r0 + 3 * DD] = __float2bfloat16(oacc[dt][3] * li3);
    }
}

// ---------------- fp32 -> bf16 convert, padding + optional row interleave ---
__device__ inline void cvt_one(const float* __restrict__ src, bf16* __restrict__ dst,
                               int Msrc, int Ksrc, int Kdst, int rmul, int radd,
                               int i4) {
    int i = i4 * 4;
    int r = i / Kdst, c = i - r * Kdst;
    ushort4 o;
    if (r < Msrc && c + 4 <= Ksrc && (Ksrc & 3) == 0) {
        float4 v = *(const float4*)(src + (size_t)r * Ksrc + c);
        o.x = f2b(v.x); o.y = f2b(v.y); o.z = f2b(v.z); o.w = f2b(v.w);
    } else {
        float v0 = (r < Msrc && c + 0 < Ksrc) ? src[(size_t)r * Ksrc + c + 0] : 0.0f;
        float v1 = (r < Msrc && c + 1 < Ksrc) ? src[(size_t)r * Ksrc + c + 1] : 0.0f;
        float v2 = (r < Msrc && c + 2 < Ksrc) ? src[(size_t)r * Ksrc + c + 2] : 0.0f;
        float v3 = (r < Msrc && c + 3 < Ksrc) ? src[(size_t)r * Ksrc + c + 3] : 0.0f;
        o.x = f2b(v0); o.y = f2b(v1); o.z = f2b(v2); o.w = f2b(v3);
    }
    *(ushort4*)(dst + ((size_t)(r * rmul + radd) * Kdst + c)) = o;
}

__global__ void cvt_pad_k(const float* __restrict__ src, bf16* __restrict__ dst,
                          int Msrc, int Ksrc, int Kdst, int total4) {
    for (int i4 = blockIdx.x * 256 + threadIdx.x; i4 < total4; i4 += gridDim.x * 256)
        cvt_one(src, dst, Msrc, Ksrc, Kdst, 1, 0, i4);
}

// flat load-balanced 6-job weight conversion (prefix-sum partitioned)
struct CvtJobs {
    const float* src[6];
    bf16* dst[6];
    int Msrc[6], Ksrc[6], Kdst[6], rmul[6], radd[6];
    int pfx[7];
};
__global__ void cvt_fused_k(CvtJobs j) {
    int total = j.pfx[6];
    for (int g = blockIdx.x * 256 + threadIdx.x; g < total; g += gridDim.x * 256) {
        int job = 0;
#pragma unroll
        for (int q = 1; q < 6; q++) job += (g >= j.pfx[q]) ? 1 : 0;
        int i4 = g - j.pfx[job];
        cvt_one(j.src[job], j.dst[job], j.Msrc[job], j.Ksrc[job], j.Kdst[job],
                j.rmul[job], j.radd[job], i4);
    }
}

// ---------------- bf16 MFMA GEMM: C[N,M] = A[N,K] @ W[M,K]^T ----------------
// BK=64 (128-B LDS rows), XOR swizzle cb ^= (row&7)<<4 both-sides.
// m97 single-buffer 2-barrier core. BM in {64,128,256}, BN in {64,128}.
// MODE 0: C fp32 NT. MODE 1: += res. MODE 3: silu-fused.
// MODE 4: rope-fused qkv epilogue; V written TRANSPOSED direct to vt.
template <int MODE, int BM, int BN>
__global__ __launch_bounds__(256) void gemm_bt(const bf16* __restrict__ A,
                                               const bf16* __restrict__ W16,
                                               const float* res, void* Cv,
                                               int N, int M, int K,
                                               const float* __restrict__ st,
                                               const float* __restrict__ ct,
                                               bf16* qp, bf16* kp, bf16* vt) {
    constexpr int MF = BM / 32;
    constexpr int NF = BN / 32;
    constexpr int ACH = BM / 32;
    constexpr int BCH = BN / 32;
    __shared__ __align__(16) bf16 As[BM * 64];
    __shared__ __align__(16) bf16 Bs[BN * 64];

    int t = threadIdx.x;
    int nnt = N / BM;
    int nmt = M / BN;
    int nwg = nmt * nnt;
    int orig = blockIdx.x;
    int q8 = nwg >> 3;
    int wgid = (orig & 7) * q8 + (orig >> 3);   // XCD-chunked, bijective (nwg%8==0)
    int mt, nt;
    if constexpr (BM == 128 && BN == 128) {      // 2m x 16n supertile
        int stile = wgid >> 5, rem = wgid & 31;
        mt = (stile << 1) + (rem & 1);
        nt = rem >> 1;
    } else {                                     // n-fastest
        mt = wgid / nnt;
        nt = wgid - mt * nnt;
    }
    int m0 = mt * BN;
    int n0 = nt * BM;

    int lane = t & 63;
    int wave = t >> 6;
    int wr = (wave >> 1) * (BM / 2);
    int wc = (wave & 1) * (BN / 2);
    int qi = lane & 15;
    int g4 = lane >> 4;

    int arow[ACH], asc[ACH], apos[ACH];
#pragma unroll
    for (int i = 0; i < ACH; i++) {
        int p = (t + i * 256) * 16;
        arow[i] = p >> 7;
        asc[i] = (p & 127) ^ ((arow[i] & 7) << 4);
        apos[i] = p;
    }
    int brow[BCH], bsc[BCH], bpos[BCH];
#pragma unroll
    for (int i = 0; i < BCH; i++) {
        int p = (t + i * 256) * 16;
        brow[i] = p >> 7;
        bsc[i] = (p & 127) ^ ((brow[i] & 7) << 4);
        bpos[i] = p;
    }

    f32x4 acc[MF][NF] = {};

    for (int k0 = 0; k0 < K; k0 += 64) {
        __syncthreads();
#pragma unroll
        for (int i = 0; i < ACH; i++)
            GLOAD16(A + (size_t)(n0 + arow[i]) * K + k0 + (asc[i] >> 1),
                    (char*)As + apos[i]);
#pragma unroll
        for (int i = 0; i < BCH; i++)
            GLOAD16(W16 + (size_t)(m0 + brow[i]) * K + k0 + (bsc[i] >> 1),
                    (char*)Bs + bpos[i]);
        __syncthreads();

#pragma unroll
        for (int h = 0; h < 2; h++) {
            int cb = h * 64 + g4 * 16;
            bf16x8 af[MF], bfr[NF];
#pragma unroll
            for (int m = 0; m < MF; m++) {
                int r = wr + m * 16 + qi;
                af[m] = *(const bf16x8*)((const char*)As + r * 128 + (cb ^ ((r & 7) << 4)));
            }
#pragma unroll
            for (int n = 0; n < NF; n++) {
                int r = wc + n * 16 + qi;
                bfr[n] = *(const bf16x8*)((const char*)Bs + r * 128 + (cb ^ ((r & 7) << 4)));
            }
#pragma unroll
            for (int m = 0; m < MF; m++)
#pragma unroll
                for (int n = 0; n < NF; n++)
                    acc[m][n] = __builtin_amdgcn_mfma_f32_16x16x32_bf16(af[m], bfr[n], acc[m][n], 0, 0, 0);
        }
    }

    int colb = m0 + wc + qi;
    int rowb = n0 + wr + g4 * 4;

    if constexpr (MODE == 0) {
        float* Cf = (float*)Cv;
#pragma unroll
        for (int m = 0; m < MF; m++) {
#pragma unroll
            for (int n = 0; n < NF; n++) {
#pragma unroll
                for (int r = 0; r < 4; r++) {
                    size_t off = (size_t)(rowb + m * 16 + r) * M + (colb + n * 16);
                    __builtin_nontemporal_store(acc[m][n][r], Cf + off);
                }
            }
        }
    } else if constexpr (MODE == 1) {
        float* Cf = (float*)Cv;
#pragma unroll
        for (int m = 0; m < MF; m++) {
#pragma unroll
            for (int n = 0; n < NF; n++) {
#pragma unroll
                for (int r = 0; r < 4; r++) {
                    size_t off = (size_t)(rowb + m * 16 + r) * M + (colb + n * 16);
                    Cf[off] = acc[m][n][r] + res[off];
                }
            }
        }
    } else if constexpr (MODE == 3) {
        bf16* Cb = (bf16*)Cv;
        int M2 = M >> 1;
        bool even = (lane & 1) == 0;
#pragma unroll
        for (int m = 0; m < MF; m++) {
#pragma unroll
            for (int n = 0; n < NF; n++) {
#pragma unroll
                for (int r = 0; r < 4; r++) {
                    float own = acc[m][n][r];
                    float oth = __shfl_xor(own, 1);
                    if (even) {
                        float sv = own / (1.0f + __expf(-own)) * oth;
                        int oc = (colb + n * 16) >> 1;
                        Cb[(size_t)(rowb + m * 16 + r) * M2 + oc] = __float2bfloat16(sv);
                    }
                }
            }
        }
    } else if constexpr (MODE == 4) {
        int h = (m0 + wc) >> 6;
#pragma unroll
        for (int m = 0; m < MF; m++) {
            if (h < 20) {
#pragma unroll
                for (int r = 0; r < 4; r++) {
                    int row = rowb + m * 16 + r;
                    int tt = row & (TT - 1);
                    int b = row >> 10;
#pragma unroll
                    for (int n = 0; n < 2; n++) {
                        int dlo = qi + n * 16;
                        float alo = acc[m][n][r];
                        float ahi = acc[m][n + 2][r];
                        float c = ct[tt * 64 + dlo];
                        float s = st[tt * 64 + dlo];
                        float olo = alo * c - ahi * s;
                        float ohi = ahi * c + alo * s;
                        if (h < 16) {
                            olo *= 0.125f; ohi *= 0.125f;
                            bf16* q = qp + (((size_t)(b * NH + h) * TT + tt) * 64);
                            q[dlo] = __float2bfloat16(olo);
                            q[dlo + 32] = __float2bfloat16(ohi);
                        } else {
                            bf16* kk = kp + (((size_t)(b * KVHN + (h - 16)) * TT + tt) * 64);
                            kk[dlo] = __float2bfloat16(olo);
                            kk[dlo + 32] = __float2bfloat16(ohi);
                        }
                    }
                }
            } else {
                int row0 = rowb + m * 16;
                int tt0 = row0 & (TT - 1);
                int b = row0 >> 10;
                int kvh = h - 20;
#pragma unroll
                for (int n = 0; n < 4; n++) {
                    int d = qi + n * 16;
                    ushort4 o;
                    o.x = f2b(acc[m][n][0]);
                    o.y = f2b(acc[m][n][1]);
                    o.z = f2b(acc[m][n][2]);
                    o.w = f2b(acc[m][n][3]);
                    *(ushort4*)(vt + ((size_t)(b * KVHN + kvh) * 64 + d) * TT + tt0) = o;
                }
            }
        }
    }
}

extern "C" void kernel_launch(void* const* d_in, const int* in_sizes, int n_in,
                              void* d_out, int out_size, void* d_ws, size_t ws_size,
                              hipStream_t stream) {
    const int* idx    = (const int*)d_in[0];
    const float* wte  = (const float*)d_in[1];
    const float* Wq   = (const float*)d_in[2];
    const float* Wkv  = (const float*)d_in[3];
    const float* Wo   = (const float*)d_in[4];
    const float* Wg   = (const float*)d_in[5];
    const float* Wu   = (const float*)d_in[6];
    const float* Wd   = (const float*)d_in[7];
    const float* rms1 = (const float*)d_in[8];
    const float* rms2 = (const float*)d_in[9];
    const float* rmsf = (const float*)d_in[10];
    float* out = (float*)d_out;

    char* ws = (char*)d_ws;
    size_t off = 0;
    float* x = (float*)(ws + off);   off += (size_t)NTOK * DD * 4;
    bf16* xn = (bf16*)(ws + off);    off += (size_t)NTOK * DD * 2;
    float* st = (float*)(ws + off);  off += (size_t)TT * 64 * 4;
    float* ct = (float*)(ws + off);  off += (size_t)TT * 64 * 4;
    bf16* yb = (bf16*)(ws + off);    off += (size_t)NTOK * DD * 2;
    bf16* gb = (bf16*)(ws + off);    off += (size_t)NTOK * IIP * 2;
    bf16* qp = (bf16*)(ws + off);    off += (size_t)NTOK * DD * 2;
    bf16* kp = (bf16*)(ws + off);    off += (size_t)BB * KVHN * TT * 64 * 2;
    bf16* vt = (bf16*)(ws + off);    off += (size_t)BB * KVHN * TT * 64 * 2;
    bf16* Wqkv_buf = (bf16*)(ws + off); off += (size_t)QKVD * DD * 2;
    bf16* Wo_buf = (bf16*)(ws + off);   off += (size_t)DD * DD * 2;
    bf16* Wgu_buf = (bf16*)(ws + off);  off += (size_t)2 * IIP * DD * 2;
    bf16* Wd_buf = (bf16*)(ws + off);   off += (size_t)DD * IIP * 2;
    bf16* wte_bf = (bf16*)(ws + off);   off += (size_t)32000 * DD * 2;

    rope_table_k<<<(TT * 64 + 255) / 256, 256, 0, stream>>>(st, ct);
    embed_k<<<NTOK, 256, 0, stream>>>(idx, wte, x);

    for (int l = 0; l < NL; ++l) {
        CvtJobs j;
        int n4[6];
        j.src[0] = Wq + (size_t)l * DD * DD;   j.dst[0] = Wqkv_buf;
        j.Msrc[0] = DD;  j.Ksrc[0] = DD;  j.Kdst[0] = DD;  n4[0] = DD * DD / 4;
        j.rmul[0] = 1; j.radd[0] = 0;
        j.src[1] = Wkv + (size_t)l * 512 * DD; j.dst[1] = Wqkv_buf + (size_t)DD * DD;
        j.Msrc[1] = 512; j.Ksrc[1] = DD;  j.Kdst[1] = DD;  n4[1] = 512 * DD / 4;
        j.rmul[1] = 1; j.radd[1] = 0;
        j.src[2] = Wo + (size_t)l * DD * DD;   j.dst[2] = Wo_buf;
        j.Msrc[2] = DD;  j.Ksrc[2] = DD;  j.Kdst[2] = DD;  n4[2] = DD * DD / 4;
        j.rmul[2] = 1; j.radd[2] = 0;
        j.src[3] = Wg + (size_t)l * II * DD;   j.dst[3] = Wgu_buf;   // rows 2i
        j.Msrc[3] = II;  j.Ksrc[3] = DD;  j.Kdst[3] = DD;  n4[3] = IIP * DD / 4;
        j.rmul[3] = 2; j.radd[3] = 0;
        j.src[4] = Wu + (size_t)l * II * DD;   j.dst[4] = Wgu_buf;   // rows 2i+1
        j.Msrc[4] = II;  j.Ksrc[4] = DD;  j.Kdst[4] = DD;  n4[4] = IIP * DD / 4;
        j.rmul[4] = 2; j.radd[4] = 1;
        j.src[5] = Wd + (size_t)l * DD * II;   j.dst[5] = Wd_buf;
        j.Msrc[5] = DD;  j.Ksrc[5] = II;  j.Kdst[5] = IIP; n4[5] = DD * IIP / 4;
        j.rmul[5] = 1; j.radd[5] = 0;
        j.pfx[0] = 0;
        for (int q = 0; q < 6; q++) j.pfx[q + 1] = j.pfx[q] + n4[q];
        cvt_fused_k<<<2048, 256, 0, stream>>>(j);

        // --- attention block ---
        rmsnorm_k<<<NTOK, 256, 0, stream>>>(x, rms1 + (size_t)l * DD, xn);
        gemm_bt<4, 64, 128><<<(QKVD / 128) * (NTOK / 64), 256, 0, stream>>>(
            xn, Wqkv_buf, nullptr, nullptr, NTOK, QKVD, DD, st, ct, qp, kp, vt);
        attn_mfma_k<<<512, 256, 0, stream>>>(qp, kp, vt, yb);
        gemm_bt<1, 64, 64><<<(DD / 64) * (NTOK / 64), 256, 0, stream>>>(
            yb, Wo_buf, x, x, NTOK, DD, DD, nullptr, nullptr, nullptr, nullptr, nullptr);
        // --- mlp block ---
        rmsnorm_k<<<NTOK, 256, 0, stream>>>(x, rms2 + (size_t)l * DD, xn);
        gemm_bt<3, 128, 128><<<(2 * IIP / 128) * (NTOK / 128), 256, 0, stream>>>(
            xn, Wgu_buf, nullptr, gb, NTOK, 2 * IIP, DD, nullptr, nullptr, nullptr, nullptr, nullptr);
        gemm_bt<1, 64, 64><<<(DD / 64) * (NTOK / 64), 256, 0, stream>>>(
            gb, Wd_buf, x, x, NTOK, DD, IIP, nullptr, nullptr, nullptr, nullptr, nullptr);
    }

    // --- final norm + tied lm_head (256x64 BK=64 swizzled, n-fastest, NT) ---
    rmsnorm_k<<<NTOK, 256, 0, stream>>>(x, rmsf, xn);
    cvt_pad_k<<<2048, 256, 0, stream>>>(wte, wte_bf, 32000, DD, DD, 32000 * DD / 4);
    gemm_bt<0, 256, 64><<<(32000 / 64) * (NTOK / 256), 256, 0, stream>>>(
        xn, wte_bf, nullptr, out, NTOK, 32000, DD, nullptr, nullptr, nullptr, nullptr, nullptr);
}

// Round 20
// 800.759 us; speedup vs baseline: 1.0150x; 1.0150x over previous
//
#include <hip/hip_runtime.h>
#include <hip/hip_bf16.h>
#include <math.h>

#define BB 2
#define TT 1024
#define DD 1024
#define NH 16
#define KVHN 4
#define NL 4
#define II 2730
#define IIP 2816
#define NTOK (BB * TT)
#define QKVD 1536
#define KSTR 72

typedef __hip_bfloat16 bf16;
typedef __attribute__((ext_vector_type(8))) short bf16x8;
typedef __attribute__((ext_vector_type(4))) float f32x4;

#define GLOAD16(gp, lp)                                                        \
    __builtin_amdgcn_global_load_lds(                                          \
        (const __attribute__((address_space(1))) unsigned int*)(gp),           \
        (__attribute__((address_space(3))) unsigned int*)(lp), 16, 0, 0)

__device__ inline float b2f(unsigned short u) {
    union { unsigned int i; float f; } v;
    v.i = (unsigned int)u << 16;
    return v.f;
}
__device__ inline unsigned short f2b(float f) {
    __hip_bfloat16 b = __float2bfloat16(f);
    return *(unsigned short*)&b;
}

// ---------------- rope sin/cos table ----------------
__global__ void rope_table_k(float* __restrict__ st, float* __restrict__ ct) {
    int i = blockIdx.x * 256 + threadIdx.x;
    if (i >= TT * 64) return;
    int t = i >> 6, d = i & 63;
    float freq = powf(10000.0f, (float)(d & 31) / 32.0f);
    float ang = (float)t / freq;
    st[i] = sinf(ang);
    ct[i] = cosf(ang);
}

// ---------------- embedding gather (fp32 residual) ----------------
__global__ __launch_bounds__(256) void embed_k(const int* __restrict__ idx,
                                               const float* __restrict__ wte,
                                               float* __restrict__ x) {
    int row = blockIdx.x;
    int tok = idx[row];
    const float4* src = (const float4*)(wte + (size_t)tok * DD);
    float4* dst = (float4*)(x + (size_t)row * DD);
    dst[threadIdx.x] = src[threadIdx.x];
}

// ---------------- rmsnorm: fp32 in -> bf16 out ----------------
__global__ __launch_bounds__(256) void rmsnorm_k(const float* __restrict__ x,
                                                 const float* __restrict__ w,
                                                 bf16* __restrict__ o) {
    int row = blockIdx.x;
    float4 v = ((const float4*)(x + (size_t)row * DD))[threadIdx.x];
    float s = v.x * v.x + v.y * v.y + v.z * v.z + v.w * v.w;
#pragma unroll
    for (int off = 32; off > 0; off >>= 1) s += __shfl_down(s, off);
    __shared__ float red[4];
    if ((threadIdx.x & 63) == 0) red[threadIdx.x >> 6] = s;
    __syncthreads();
    float tot = red[0] + red[1] + red[2] + red[3];
    float r = rsqrtf(tot * (1.0f / DD) + 1e-6f);
    float4 wv = ((const float4*)w)[threadIdx.x];
    size_t base = (size_t)row * DD + threadIdx.x * 4;
    ushort4 ov;
    ov.x = f2b(v.x * r * wv.x);
    ov.y = f2b(v.y * r * wv.y);
    ov.z = f2b(v.z * r * wv.z);
    ov.w = f2b(v.w * r * wv.w);
    *(ushort4*)(o + base) = ov;
}

// ---------------- MFMA flash attention (bf16, causal, GQA h%4) ------------
// 1D grid of 512, complementary qt pairing (uniform 17 KV-tiles per CU).
__global__ __launch_bounds__(256) void attn_mfma_k(const bf16* __restrict__ qp,
                                                   const bf16* __restrict__ kp,
                                                   const bf16* __restrict__ vt,
                                                   bf16* __restrict__ y) {
    int i = blockIdx.x;
    int b = i >> 8;
    int base = i & 255;
    int h = base >> 4;
    int q4 = base & 15;
    int qt = b ? (15 - q4) : q4;
    int kvh = h & (KVHN - 1);

    __shared__ __align__(16) bf16 Ks[64][KSTR];
    __shared__ __align__(16) bf16 Vt[64][KSTR];
    __shared__ __align__(16) bf16 Ps[4][16][KSTR];

    int tid = threadIdx.x;
    int lane = tid & 63;
    int w = tid >> 6;
    int qi = lane & 15;
    int g = lane >> 4;

    const bf16* qbase = qp + (((size_t)(b * NH + h) * TT + qt * 64 + w * 16 + qi) * 64);
    bf16x8 qf0 = *(const bf16x8*)(qbase + g * 8);
    bf16x8 qf1 = *(const bf16x8*)(qbase + 32 + g * 8);

    const bf16* kg = kp + ((size_t)(b * KVHN + kvh) * TT) * 64;
    const bf16* vg = vt + ((size_t)(b * KVHN + kvh) * 64) * TT;

    int c0 = tid, c1 = tid + 256;
    auto ldK = [&](int kt, int c) {
        return *(const bf16x8*)(kg + (size_t)(kt * 64 + (c >> 3)) * 64 + (c & 7) * 8);
    };
    auto ldV = [&](int kt, int c) {
        return *(const bf16x8*)(vg + (size_t)(c >> 3) * TT + kt * 64 + (c & 7) * 8);
    };

    f32x4 oacc[4] = {};
    float m = -INFINITY, l = 0.0f;
    int qglob = qt * 64 + w * 16 + qi;

    bf16x8 rk0 = ldK(0, c0), rk1 = ldK(0, c1);
    bf16x8 rv0 = ldV(0, c0), rv1 = ldV(0, c1);

    for (int kt = 0; kt <= qt; ++kt) {
        __syncthreads();
        *(bf16x8*)(&Ks[c0 >> 3][(c0 & 7) * 8]) = rk0;
        *(bf16x8*)(&Ks[c1 >> 3][(c1 & 7) * 8]) = rk1;
        *(bf16x8*)(&Vt[c0 >> 3][(c0 & 7) * 8]) = rv0;
        *(bf16x8*)(&Vt[c1 >> 3][(c1 & 7) * 8]) = rv1;
        __syncthreads();

        if (kt < qt) {
            rk0 = ldK(kt + 1, c0); rk1 = ldK(kt + 1, c1);
            rv0 = ldV(kt + 1, c0); rv1 = ldV(kt + 1, c1);
        }

        f32x4 sacc[4] = {};
#pragma unroll
        for (int stt = 0; stt < 4; ++stt) {
            bf16x8 kf0 = *(const bf16x8*)(&Ks[stt * 16 + qi][g * 8]);
            bf16x8 kf1 = *(const bf16x8*)(&Ks[stt * 16 + qi][32 + g * 8]);
            sacc[stt] = __builtin_amdgcn_mfma_f32_16x16x32_bf16(kf0, qf0, sacc[stt], 0, 0, 0);
            sacc[stt] = __builtin_amdgcn_mfma_f32_16x16x32_bf16(kf1, qf1, sacc[stt], 0, 0, 0);
        }

        if (kt == qt) {
#pragma unroll
            for (int stt = 0; stt < 4; ++stt)
#pragma unroll
                for (int r = 0; r < 4; ++r) {
                    int kgl = kt * 64 + stt * 16 + g * 4 + r;
                    if (kgl > qglob) sacc[stt][r] = -INFINITY;
                }
        }

        float tmax = -INFINITY;
#pragma unroll
        for (int stt = 0; stt < 4; ++stt)
#pragma unroll
            for (int r = 0; r < 4; ++r) tmax = fmaxf(tmax, sacc[stt][r]);
        tmax = fmaxf(tmax, __shfl_xor(tmax, 16));
        tmax = fmaxf(tmax, __shfl_xor(tmax, 32));
        float mnew = fmaxf(m, tmax);
        float scale = __expf(m - mnew);
        float psum = 0.0f;
#pragma unroll
        for (int stt = 0; stt < 4; ++stt) {
            bf16 pb[4];
#pragma unroll
            for (int r = 0; r < 4; ++r) {
                float p = __expf(sacc[stt][r] - mnew);
                psum += p;
                pb[r] = __float2bfloat16(p);
            }
            *(uint2*)(&Ps[w][qi][stt * 16 + g * 4]) = *(uint2*)pb;
        }
        psum += __shfl_xor(psum, 16);
        psum += __shfl_xor(psum, 32);
        l = l * scale + psum;
        m = mnew;

        float sc0 = __shfl(scale, g * 4 + 0);
        float sc1 = __shfl(scale, g * 4 + 1);
        float sc2 = __shfl(scale, g * 4 + 2);
        float sc3 = __shfl(scale, g * 4 + 3);
#pragma unroll
        for (int dt = 0; dt < 4; ++dt) {
            oacc[dt][0] *= sc0; oacc[dt][1] *= sc1;
            oacc[dt][2] *= sc2; oacc[dt][3] *= sc3;
        }

#pragma unroll
        for (int kc = 0; kc < 2; ++kc) {
            bf16x8 pa = *(const bf16x8*)(&Ps[w][qi][kc * 32 + g * 8]);
#pragma unroll
            for (int dt = 0; dt < 4; ++dt) {
                bf16x8 vb2 = *(const bf16x8*)(&Vt[dt * 16 + qi][kc * 32 + g * 8]);
                oacc[dt] = __builtin_amdgcn_mfma_f32_16x16x32_bf16(pa, vb2, oacc[dt], 0, 0, 0);
            }
        }
    }

    float linv = 1.0f / l;
    float li0 = __shfl(linv, g * 4 + 0);
    float li1 = __shfl(linv, g * 4 + 1);
    float li2 = __shfl(linv, g * 4 + 2);
    float li3 = __shfl(linv, g * 4 + 3);
#pragma unroll
    for (int dt = 0; dt < 4; ++dt) {
        int dcol = h * 64 + dt * 16 + qi;
        size_t r0 = (size_t)(b * TT + qt * 64 + w * 16 + g * 4) * DD + dcol;
        y[r0 + 0 * DD] = __float2bfloat16(oacc[dt][0] * li0);
        y[r0 + 1 * DD] = __float2bfloat16(oacc[dt][1] * li1);
        y[r0 + 2 * DD] = __float2bfloat16(oacc[dt][2] * li2);
        y[r0 + 3 * DD] = __float2bfloat16(oacc[dt][3] * li3);
    }
}

// ---------------- fp32 -> bf16 convert, padding + optional row interleave ---
__device__ inline void cvt_one(const float* __restrict__ src, bf16* __restrict__ dst,
                               int Msrc, int Ksrc, int Kdst, int rmul, int radd,
                               int i4) {
    int i = i4 * 4;
    int r = i / Kdst, c = i - r * Kdst;
    ushort4 o;
    if (r < Msrc && c + 4 <= Ksrc && (Ksrc & 3) == 0) {
        float4 v = *(const float4*)(src + (size_t)r * Ksrc + c);
        o.x = f2b(v.x); o.y = f2b(v.y); o.z = f2b(v.z); o.w = f2b(v.w);
    } else {
        float v0 = (r < Msrc && c + 0 < Ksrc) ? src[(size_t)r * Ksrc + c + 0] : 0.0f;
        float v1 = (r < Msrc && c + 1 < Ksrc) ? src[(size_t)r * Ksrc + c + 1] : 0.0f;
        float v2 = (r < Msrc && c + 2 < Ksrc) ? src[(size_t)r * Ksrc + c + 2] : 0.0f;
        float v3 = (r < Msrc && c + 3 < Ksrc) ? src[(size_t)r * Ksrc + c + 3] : 0.0f;
        o.x = f2b(v0); o.y = f2b(v1); o.z = f2b(v2); o.w = f2b(v3);
    }
    *(ushort4*)(dst + ((size_t)(r * rmul + radd) * Kdst + c)) = o;
}

__global__ void cvt_pad_k(const float* __restrict__ src, bf16* __restrict__ dst,
                          int Msrc, int Ksrc, int Kdst, int total4) {
    for (int i4 = blockIdx.x * 256 + threadIdx.x; i4 < total4; i4 += gridDim.x * 256)
        cvt_one(src, dst, Msrc, Ksrc, Kdst, 1, 0, i4);
}

// flat load-balanced 6-job weight conversion (prefix-sum partitioned)
struct CvtJobs {
    const float* src[6];
    bf16* dst[6];
    int Msrc[6], Ksrc[6], Kdst[6], rmul[6], radd[6];
    int pfx[7];
};
__global__ void cvt_fused_k(CvtJobs j) {
    int total = j.pfx[6];
    for (int g = blockIdx.x * 256 + threadIdx.x; g < total; g += gridDim.x * 256) {
        int job = 0;
#pragma unroll
        for (int q = 1; q < 6; q++) job += (g >= j.pfx[q]) ? 1 : 0;
        int i4 = g - j.pfx[job];
        cvt_one(j.src[job], j.dst[job], j.Msrc[job], j.Ksrc[job], j.Kdst[job],
                j.rmul[job], j.radd[job], i4);
    }
}

// ---------------- bf16 MFMA GEMM: C[N,M] = A[N,K] @ W[M,K]^T ----------------
// BK=64 (128-B LDS rows), XOR swizzle cb ^= (row&7)<<4 both-sides.
// m97 single-buffer 2-barrier core.
// MODE 0: C fp32 NT. MODE 1: += res. MODE 3: silu-fused.
// MODE 4: rope-fused qkv epilogue; V written TRANSPOSED direct to vt.
template <int MODE, int BM, int BN>
__global__ __launch_bounds__(256) void gemm_bt(const bf16* __restrict__ A,
                                               const bf16* __restrict__ W16,
                                               const float* res, void* Cv,
                                               int N, int M, int K,
                                               const float* __restrict__ st,
                                               const float* __restrict__ ct,
                                               bf16* qp, bf16* kp, bf16* vt) {
    constexpr int MF = BM / 32;
    constexpr int NF = BN / 32;
    constexpr int ACH = BM / 32;
    constexpr int BCH = BN / 32;
    __shared__ __align__(16) bf16 As[BM * 64];
    __shared__ __align__(16) bf16 Bs[BN * 64];

    int t = threadIdx.x;
    int nnt = N / BM;
    int nmt = M / BN;
    int nwg = nmt * nnt;
    int orig = blockIdx.x;
    int q8 = nwg >> 3;
    int wgid = (orig & 7) * q8 + (orig >> 3);   // XCD-chunked, bijective (nwg%8==0)
    int mt, nt;
    if constexpr (BM == 128 && BN == 128) {      // 2m x 16n supertile
        int stile = wgid >> 5, rem = wgid & 31;
        mt = (stile << 1) + (rem & 1);
        nt = rem >> 1;
    } else {                                     // n-fastest
        mt = wgid / nnt;
        nt = wgid - mt * nnt;
    }
    int m0 = mt * BN;
    int n0 = nt * BM;

    int lane = t & 63;
    int wave = t >> 6;
    int wr = (wave >> 1) * (BM / 2);
    int wc = (wave & 1) * (BN / 2);
    int qi = lane & 15;
    int g4 = lane >> 4;

    int arow[ACH], asc[ACH], apos[ACH];
#pragma unroll
    for (int i = 0; i < ACH; i++) {
        int p = (t + i * 256) * 16;
        arow[i] = p >> 7;
        asc[i] = (p & 127) ^ ((arow[i] & 7) << 4);
        apos[i] = p;
    }
    int brow[BCH], bsc[BCH], bpos[BCH];
#pragma unroll
    for (int i = 0; i < BCH; i++) {
        int p = (t + i * 256) * 16;
        brow[i] = p >> 7;
        bsc[i] = (p & 127) ^ ((brow[i] & 7) << 4);
        bpos[i] = p;
    }

    f32x4 acc[MF][NF] = {};

    for (int k0 = 0; k0 < K; k0 += 64) {
        __syncthreads();
#pragma unroll
        for (int i = 0; i < ACH; i++)
            GLOAD16(A + (size_t)(n0 + arow[i]) * K + k0 + (asc[i] >> 1),
                    (char*)As + apos[i]);
#pragma unroll
        for (int i = 0; i < BCH; i++)
            GLOAD16(W16 + (size_t)(m0 + brow[i]) * K + k0 + (bsc[i] >> 1),
                    (char*)Bs + bpos[i]);
        __syncthreads();

#pragma unroll
        for (int h = 0; h < 2; h++) {
            int cb = h * 64 + g4 * 16;
            bf16x8 af[MF], bfr[NF];
#pragma unroll
            for (int m = 0; m < MF; m++) {
                int r = wr + m * 16 + qi;
                af[m] = *(const bf16x8*)((const char*)As + r * 128 + (cb ^ ((r & 7) << 4)));
            }
#pragma unroll
            for (int n = 0; n < NF; n++) {
                int r = wc + n * 16 + qi;
                bfr[n] = *(const bf16x8*)((const char*)Bs + r * 128 + (cb ^ ((r & 7) << 4)));
            }
#pragma unroll
            for (int m = 0; m < MF; m++)
#pragma unroll
                for (int n = 0; n < NF; n++)
                    acc[m][n] = __builtin_amdgcn_mfma_f32_16x16x32_bf16(af[m], bfr[n], acc[m][n], 0, 0, 0);
        }
    }

    int colb = m0 + wc + qi;
    int rowb = n0 + wr + g4 * 4;

    if constexpr (MODE == 0) {
        float* Cf = (float*)Cv;
#pragma unroll
        for (int m = 0; m < MF; m++) {
#pragma unroll
            for (int n = 0; n < NF; n++) {
#pragma unroll
                for (int r = 0; r < 4; r++) {
                    size_t off = (size_t)(rowb + m * 16 + r) * M + (colb + n * 16);
                    __builtin_nontemporal_store(acc[m][n][r], Cf + off);
                }
            }
        }
    } else if constexpr (MODE == 1) {
        float* Cf = (float*)Cv;
#pragma unroll
        for (int m = 0; m < MF; m++) {
#pragma unroll
            for (int n = 0; n < NF; n++) {
#pragma unroll
                for (int r = 0; r < 4; r++) {
                    size_t off = (size_t)(rowb + m * 16 + r) * M + (colb + n * 16);
                    Cf[off] = acc[m][n][r] + res[off];
                }
            }
        }
    } else if constexpr (MODE == 3) {
        bf16* Cb = (bf16*)Cv;
        int M2 = M >> 1;
        bool even = (lane & 1) == 0;
#pragma unroll
        for (int m = 0; m < MF; m++) {
#pragma unroll
            for (int n = 0; n < NF; n++) {
#pragma unroll
                for (int r = 0; r < 4; r++) {
                    float own = acc[m][n][r];
                    float oth = __shfl_xor(own, 1);
                    if (even) {
                        float sv = own / (1.0f + __expf(-own)) * oth;
                        int oc = (colb + n * 16) >> 1;
                        Cb[(size_t)(rowb + m * 16 + r) * M2 + oc] = __float2bfloat16(sv);
                    }
                }
            }
        }
    } else if constexpr (MODE == 4) {
        int h = (m0 + wc) >> 6;
#pragma unroll
        for (int m = 0; m < MF; m++) {
            if (h < 20) {
#pragma unroll
                for (int r = 0; r < 4; r++) {
                    int row = rowb + m * 16 + r;
                    int tt = row & (TT - 1);
                    int b = row >> 10;
#pragma unroll
                    for (int n = 0; n < 2; n++) {
                        int dlo = qi + n * 16;
                        float alo = acc[m][n][r];
                        float ahi = acc[m][n + 2][r];
                        float c = ct[tt * 64 + dlo];
                        float s = st[tt * 64 + dlo];
                        float olo = alo * c - ahi * s;
                        float ohi = ahi * c + alo * s;
                        if (h < 16) {
                            olo *= 0.125f; ohi *= 0.125f;
                            bf16* q = qp + (((size_t)(b * NH + h) * TT + tt) * 64);
                            q[dlo] = __float2bfloat16(olo);
                            q[dlo + 32] = __float2bfloat16(ohi);
                        } else {
                            bf16* kk = kp + (((size_t)(b * KVHN + (h - 16)) * TT + tt) * 64);
                            kk[dlo] = __float2bfloat16(olo);
                            kk[dlo + 32] = __float2bfloat16(ohi);
                        }
                    }
                }
            } else {
                int row0 = rowb + m * 16;
                int tt0 = row0 & (TT - 1);
                int b = row0 >> 10;
                int kvh = h - 20;
#pragma unroll
                for (int n = 0; n < 4; n++) {
                    int d = qi + n * 16;
                    ushort4 o;
                    o.x = f2b(acc[m][n][0]);
                    o.y = f2b(acc[m][n][1]);
                    o.z = f2b(acc[m][n][2]);
                    o.w = f2b(acc[m][n][3]);
                    *(ushort4*)(vt + ((size_t)(b * KVHN + kvh) * 64 + d) * TT + tt0) = o;
                }
            }
        }
    }
}

extern "C" void kernel_launch(void* const* d_in, const int* in_sizes, int n_in,
                              void* d_out, int out_size, void* d_ws, size_t ws_size,
                              hipStream_t stream) {
    const int* idx    = (const int*)d_in[0];
    const float* wte  = (const float*)d_in[1];
    const float* Wq   = (const float*)d_in[2];
    const float* Wkv  = (const float*)d_in[3];
    const float* Wo   = (const float*)d_in[4];
    const float* Wg   = (const float*)d_in[5];
    const float* Wu   = (const float*)d_in[6];
    const float* Wd   = (const float*)d_in[7];
    const float* rms1 = (const float*)d_in[8];
    const float* rms2 = (const float*)d_in[9];
    const float* rmsf = (const float*)d_in[10];
    float* out = (float*)d_out;

    char* ws = (char*)d_ws;
    size_t off = 0;
    float* x = (float*)(ws + off);   off += (size_t)NTOK * DD * 4;
    bf16* xn = (bf16*)(ws + off);    off += (size_t)NTOK * DD * 2;
    float* st = (float*)(ws + off);  off += (size_t)TT * 64 * 4;
    float* ct = (float*)(ws + off);  off += (size_t)TT * 64 * 4;
    bf16* yb = (bf16*)(ws + off);    off += (size_t)NTOK * DD * 2;
    bf16* gb = (bf16*)(ws + off);    off += (size_t)NTOK * IIP * 2;
    bf16* qp = (bf16*)(ws + off);    off += (size_t)NTOK * DD * 2;
    bf16* kp = (bf16*)(ws + off);    off += (size_t)BB * KVHN * TT * 64 * 2;
    bf16* vt = (bf16*)(ws + off);    off += (size_t)BB * KVHN * TT * 64 * 2;
    bf16* Wqkv_buf = (bf16*)(ws + off); off += (size_t)QKVD * DD * 2;
    bf16* Wo_buf = (bf16*)(ws + off);   off += (size_t)DD * DD * 2;
    bf16* Wgu_buf = (bf16*)(ws + off);  off += (size_t)2 * IIP * DD * 2;
    bf16* Wd_buf = (bf16*)(ws + off);   off += (size_t)DD * IIP * 2;
    bf16* wte_bf = (bf16*)(ws + off);   off += (size_t)32000 * DD * 2;

    rope_table_k<<<(TT * 64 + 255) / 256, 256, 0, stream>>>(st, ct);
    embed_k<<<NTOK, 256, 0, stream>>>(idx, wte, x);

    for (int l = 0; l < NL; ++l) {
        CvtJobs j;
        int n4[6];
        j.src[0] = Wq + (size_t)l * DD * DD;   j.dst[0] = Wqkv_buf;
        j.Msrc[0] = DD;  j.Ksrc[0] = DD;  j.Kdst[0] = DD;  n4[0] = DD * DD / 4;
        j.rmul[0] = 1; j.radd[0] = 0;
        j.src[1] = Wkv + (size_t)l * 512 * DD; j.dst[1] = Wqkv_buf + (size_t)DD * DD;
        j.Msrc[1] = 512; j.Ksrc[1] = DD;  j.Kdst[1] = DD;  n4[1] = 512 * DD / 4;
        j.rmul[1] = 1; j.radd[1] = 0;
        j.src[2] = Wo + (size_t)l * DD * DD;   j.dst[2] = Wo_buf;
        j.Msrc[2] = DD;  j.Ksrc[2] = DD;  j.Kdst[2] = DD;  n4[2] = DD * DD / 4;
        j.rmul[2] = 1; j.radd[2] = 0;
        j.src[3] = Wg + (size_t)l * II * DD;   j.dst[3] = Wgu_buf;   // rows 2i
        j.Msrc[3] = II;  j.Ksrc[3] = DD;  j.Kdst[3] = DD;  n4[3] = IIP * DD / 4;
        j.rmul[3] = 2; j.radd[3] = 0;
        j.src[4] = Wu + (size_t)l * II * DD;   j.dst[4] = Wgu_buf;   // rows 2i+1
        j.Msrc[4] = II;  j.Ksrc[4] = DD;  j.Kdst[4] = DD;  n4[4] = IIP * DD / 4;
        j.rmul[4] = 2; j.radd[4] = 1;
        j.src[5] = Wd + (size_t)l * DD * II;   j.dst[5] = Wd_buf;
        j.Msrc[5] = DD;  j.Ksrc[5] = II;  j.Kdst[5] = IIP; n4[5] = DD * IIP / 4;
        j.rmul[5] = 1; j.radd[5] = 0;
        j.pfx[0] = 0;
        for (int q = 0; q < 6; q++) j.pfx[q + 1] = j.pfx[q] + n4[q];
        cvt_fused_k<<<2048, 256, 0, stream>>>(j);

        // --- attention block ---
        rmsnorm_k<<<NTOK, 256, 0, stream>>>(x, rms1 + (size_t)l * DD, xn);
        gemm_bt<4, 64, 128><<<(QKVD / 128) * (NTOK / 64), 256, 0, stream>>>(
            xn, Wqkv_buf, nullptr, nullptr, NTOK, QKVD, DD, st, ct, qp, kp, vt);
        attn_mfma_k<<<512, 256, 0, stream>>>(qp, kp, vt, yb);
        gemm_bt<1, 64, 64><<<(DD / 64) * (NTOK / 64), 256, 0, stream>>>(
            yb, Wo_buf, x, x, NTOK, DD, DD, nullptr, nullptr, nullptr, nullptr, nullptr);
        // --- mlp block ---
        rmsnorm_k<<<NTOK, 256, 0, stream>>>(x, rms2 + (size_t)l * DD, xn);
        gemm_bt<3, 128, 128><<<(2 * IIP / 128) * (NTOK / 128), 256, 0, stream>>>(
            xn, Wgu_buf, nullptr, gb, NTOK, 2 * IIP, DD, nullptr, nullptr, nullptr, nullptr, nullptr);
        gemm_bt<1, 64, 64><<<(DD / 64) * (NTOK / 64), 256, 0, stream>>>(
            gb, Wd_buf, x, x, NTOK, DD, IIP, nullptr, nullptr, nullptr, nullptr, nullptr);
    }

    // --- final norm + tied lm_head (128x64 BK=64 swizzled, n-fastest, NT) ---
    rmsnorm_k<<<NTOK, 256, 0, stream>>>(x, rmsf, xn);
    cvt_pad_k<<<2048, 256, 0, stream>>>(wte, wte_bf, 32000, DD, DD, 32000 * DD / 4);
    gemm_bt<0, 128, 64><<<(32000 / 64) * (NTOK / 128), 256, 0, stream>>>(
        xn, wte_bf, nullptr, out, NTOK, 32000, DD, nullptr, nullptr, nullptr, nullptr, nullptr);
}

// Round 22
// 795.948 us; speedup vs baseline: 1.0211x; 1.0060x over previous
//
#include <hip/hip_runtime.h>
#include <hip/hip_bf16.h>
#include <math.h>

#define BB 2
#define TT 1024
#define DD 1024
#define NH 16
#define KVHN 4
#define NL 4
#define II 2730
#define IIP 2816
#define NTOK (BB * TT)
#define QKVD 1536
#define KSTR 72

typedef __hip_bfloat16 bf16;
typedef __attribute__((ext_vector_type(8))) short bf16x8;
typedef __attribute__((ext_vector_type(4))) float f32x4;

#define GLOAD16(gp, lp)                                                        \
    __builtin_amdgcn_global_load_lds(                                          \
        (const __attribute__((address_space(1))) unsigned int*)(gp),           \
        (__attribute__((address_space(3))) unsigned int*)(lp), 16, 0, 0)

__device__ inline float b2f(unsigned short u) {
    union { unsigned int i; float f; } v;
    v.i = (unsigned int)u << 16;
    return v.f;
}
__device__ inline unsigned short f2b(float f) {
    __hip_bfloat16 b = __float2bfloat16(f);
    return *(unsigned short*)&b;
}

// ---------------- rope sin/cos table ----------------
__global__ void rope_table_k(float* __restrict__ st, float* __restrict__ ct) {
    int i = blockIdx.x * 256 + threadIdx.x;
    if (i >= TT * 64) return;
    int t = i >> 6, d = i & 63;
    float freq = powf(10000.0f, (float)(d & 31) / 32.0f);
    float ang = (float)t / freq;
    st[i] = sinf(ang);
    ct[i] = cosf(ang);
}

// ---------------- embedding gather (fp32 residual) ----------------
__global__ __launch_bounds__(256) void embed_k(const int* __restrict__ idx,
                                               const float* __restrict__ wte,
                                               float* __restrict__ x) {
    int row = blockIdx.x;
    int tok = idx[row];
    const float4* src = (const float4*)(wte + (size_t)tok * DD);
    float4* dst = (float4*)(x + (size_t)row * DD);
    dst[threadIdx.x] = src[threadIdx.x];
}

// ---------------- rmsnorm: fp32 in -> bf16 out ----------------
__global__ __launch_bounds__(256) void rmsnorm_k(const float* __restrict__ x,
                                                 const float* __restrict__ w,
                                                 bf16* __restrict__ o) {
    int row = blockIdx.x;
    float4 v = ((const float4*)(x + (size_t)row * DD))[threadIdx.x];
    float s = v.x * v.x + v.y * v.y + v.z * v.z + v.w * v.w;
#pragma unroll
    for (int off = 32; off > 0; off >>= 1) s += __shfl_down(s, off);
    __shared__ float red[4];
    if ((threadIdx.x & 63) == 0) red[threadIdx.x >> 6] = s;
    __syncthreads();
    float tot = red[0] + red[1] + red[2] + red[3];
    float r = rsqrtf(tot * (1.0f / DD) + 1e-6f);
    float4 wv = ((const float4*)w)[threadIdx.x];
    size_t base = (size_t)row * DD + threadIdx.x * 4;
    ushort4 ov;
    ov.x = f2b(v.x * r * wv.x);
    ov.y = f2b(v.y * r * wv.y);
    ov.z = f2b(v.z * r * wv.z);
    ov.w = f2b(v.w * r * wv.w);
    *(ushort4*)(o + base) = ov;
}

// ---------------- MFMA flash attention (bf16, causal, GQA h%4) ------------
// 1D grid of 512, complementary qt pairing (uniform 17 KV-tiles per CU).
__global__ __launch_bounds__(256) void attn_mfma_k(const bf16* __restrict__ qp,
                                                   const bf16* __restrict__ kp,
                                                   const bf16* __restrict__ vt,
                                                   bf16* __restrict__ y) {
    int i = blockIdx.x;
    int b = i >> 8;
    int base = i & 255;
    int h = base >> 4;
    int q4 = base & 15;
    int qt = b ? (15 - q4) : q4;
    int kvh = h & (KVHN - 1);

    __shared__ __align__(16) bf16 Ks[64][KSTR];
    __shared__ __align__(16) bf16 Vt[64][KSTR];
    __shared__ __align__(16) bf16 Ps[4][16][KSTR];

    int tid = threadIdx.x;
    int lane = tid & 63;
    int w = tid >> 6;
    int qi = lane & 15;
    int g = lane >> 4;

    const bf16* qbase = qp + (((size_t)(b * NH + h) * TT + qt * 64 + w * 16 + qi) * 64);
    bf16x8 qf0 = *(const bf16x8*)(qbase + g * 8);
    bf16x8 qf1 = *(const bf16x8*)(qbase + 32 + g * 8);

    const bf16* kg = kp + ((size_t)(b * KVHN + kvh) * TT) * 64;
    const bf16* vg = vt + ((size_t)(b * KVHN + kvh) * 64) * TT;

    int c0 = tid, c1 = tid + 256;
    auto ldK = [&](int kt, int c) {
        return *(const bf16x8*)(kg + (size_t)(kt * 64 + (c >> 3)) * 64 + (c & 7) * 8);
    };
    auto ldV = [&](int kt, int c) {
        return *(const bf16x8*)(vg + (size_t)(c >> 3) * TT + kt * 64 + (c & 7) * 8);
    };

    f32x4 oacc[4] = {};
    float m = -INFINITY, l = 0.0f;
    int qglob = qt * 64 + w * 16 + qi;

    bf16x8 rk0 = ldK(0, c0), rk1 = ldK(0, c1);
    bf16x8 rv0 = ldV(0, c0), rv1 = ldV(0, c1);

    for (int kt = 0; kt <= qt; ++kt) {
        __syncthreads();
        *(bf16x8*)(&Ks[c0 >> 3][(c0 & 7) * 8]) = rk0;
        *(bf16x8*)(&Ks[c1 >> 3][(c1 & 7) * 8]) = rk1;
        *(bf16x8*)(&Vt[c0 >> 3][(c0 & 7) * 8]) = rv0;
        *(bf16x8*)(&Vt[c1 >> 3][(c1 & 7) * 8]) = rv1;
        __syncthreads();

        if (kt < qt) {
            rk0 = ldK(kt + 1, c0); rk1 = ldK(kt + 1, c1);
            rv0 = ldV(kt + 1, c0); rv1 = ldV(kt + 1, c1);
        }

        f32x4 sacc[4] = {};
#pragma unroll
        for (int stt = 0; stt < 4; ++stt) {
            bf16x8 kf0 = *(const bf16x8*)(&Ks[stt * 16 + qi][g * 8]);
            bf16x8 kf1 = *(const bf16x8*)(&Ks[stt * 16 + qi][32 + g * 8]);
            sacc[stt] = __builtin_amdgcn_mfma_f32_16x16x32_bf16(kf0, qf0, sacc[stt], 0, 0, 0);
            sacc[stt] = __builtin_amdgcn_mfma_f32_16x16x32_bf16(kf1, qf1, sacc[stt], 0, 0, 0);
        }

        if (kt == qt) {
#pragma unroll
            for (int stt = 0; stt < 4; ++stt)
#pragma unroll
                for (int r = 0; r < 4; ++r) {
                    int kgl = kt * 64 + stt * 16 + g * 4 + r;
                    if (kgl > qglob) sacc[stt][r] = -INFINITY;
                }
        }

        float tmax = -INFINITY;
#pragma unroll
        for (int stt = 0; stt < 4; ++stt)
#pragma unroll
            for (int r = 0; r < 4; ++r) tmax = fmaxf(tmax, sacc[stt][r]);
        tmax = fmaxf(tmax, __shfl_xor(tmax, 16));
        tmax = fmaxf(tmax, __shfl_xor(tmax, 32));
        float mnew = fmaxf(m, tmax);
        float scale = __expf(m - mnew);
        float psum = 0.0f;
#pragma unroll
        for (int stt = 0; stt < 4; ++stt) {
            bf16 pb[4];
#pragma unroll
            for (int r = 0; r < 4; ++r) {
                float p = __expf(sacc[stt][r] - mnew);
                psum += p;
                pb[r] = __float2bfloat16(p);
            }
            *(uint2*)(&Ps[w][qi][stt * 16 + g * 4]) = *(uint2*)pb;
        }
        psum += __shfl_xor(psum, 16);
        psum += __shfl_xor(psum, 32);
        l = l * scale + psum;
        m = mnew;

        float sc0 = __shfl(scale, g * 4 + 0);
        float sc1 = __shfl(scale, g * 4 + 1);
        float sc2 = __shfl(scale, g * 4 + 2);
        float sc3 = __shfl(scale, g * 4 + 3);
#pragma unroll
        for (int dt = 0; dt < 4; ++dt) {
            oacc[dt][0] *= sc0; oacc[dt][1] *= sc1;
            oacc[dt][2] *= sc2; oacc[dt][3] *= sc3;
        }

#pragma unroll
        for (int kc = 0; kc < 2; ++kc) {
            bf16x8 pa = *(const bf16x8*)(&Ps[w][qi][kc * 32 + g * 8]);
#pragma unroll
            for (int dt = 0; dt < 4; ++dt) {
                bf16x8 vb2 = *(const bf16x8*)(&Vt[dt * 16 + qi][kc * 32 + g * 8]);
                oacc[dt] = __builtin_amdgcn_mfma_f32_16x16x32_bf16(pa, vb2, oacc[dt], 0, 0, 0);
            }
        }
    }

    float linv = 1.0f / l;
    float li0 = __shfl(linv, g * 4 + 0);
    float li1 = __shfl(linv, g * 4 + 1);
    float li2 = __shfl(linv, g * 4 + 2);
    float li3 = __shfl(linv, g * 4 + 3);
#pragma unroll
    for (int dt = 0; dt < 4; ++dt) {
        int dcol = h * 64 + dt * 16 + qi;
        size_t r0 = (size_t)(b * TT + qt * 64 + w * 16 + g * 4) * DD + dcol;
        y[r0 + 0 * DD] = __float2bfloat16(oacc[dt][0] * li0);
        y[r0 + 1 * DD] = __float2bfloat16(oacc[dt][1] * li1);
        y[r0 + 2 * DD] = __float2bfloat16(oacc[dt][2] * li2);
        y[r0 + 3 * DD] = __float2bfloat16(oacc[dt][3] * li3);
    }
}

// -------- fp32 -> bf16 convert (NT fp32 loads via clang ext-vector) --------
__device__ inline void cvt_one(const float* __restrict__ src, bf16* __restrict__ dst,
                               int Msrc, int Ksrc, int Kdst, int rmul, int radd,
                               int i4) {
    int i = i4 * 4;
    int r = i / Kdst, c = i - r * Kdst;
    ushort4 o;
    if (r < Msrc && c + 4 <= Ksrc && (Ksrc & 3) == 0) {
        f32x4 v = __builtin_nontemporal_load((const f32x4*)(src + (size_t)r * Ksrc + c));
        o.x = f2b(v[0]); o.y = f2b(v[1]); o.z = f2b(v[2]); o.w = f2b(v[3]);
    } else {
        float v0 = (r < Msrc && c + 0 < Ksrc) ? src[(size_t)r * Ksrc + c + 0] : 0.0f;
        float v1 = (r < Msrc && c + 1 < Ksrc) ? src[(size_t)r * Ksrc + c + 1] : 0.0f;
        float v2 = (r < Msrc && c + 2 < Ksrc) ? src[(size_t)r * Ksrc + c + 2] : 0.0f;
        float v3 = (r < Msrc && c + 3 < Ksrc) ? src[(size_t)r * Ksrc + c + 3] : 0.0f;
        o.x = f2b(v0); o.y = f2b(v1); o.z = f2b(v2); o.w = f2b(v3);
    }
    *(ushort4*)(dst + ((size_t)(r * rmul + radd) * Kdst + c)) = o;
}

__global__ void cvt_pad_k(const float* __restrict__ src, bf16* __restrict__ dst,
                          int Msrc, int Ksrc, int Kdst, int total4) {
    for (int i4 = blockIdx.x * 256 + threadIdx.x; i4 < total4; i4 += gridDim.x * 256)
        cvt_one(src, dst, Msrc, Ksrc, Kdst, 1, 0, i4);
}

// flat load-balanced 6-job weight conversion (prefix-sum partitioned)
struct CvtJobs {
    const float* src[6];
    bf16* dst[6];
    int Msrc[6], Ksrc[6], Kdst[6], rmul[6], radd[6];
    int pfx[7];
};
__global__ void cvt_fused_k(CvtJobs j) {
    int total = j.pfx[6];
    for (int g = blockIdx.x * 256 + threadIdx.x; g < total; g += gridDim.x * 256) {
        int job = 0;
#pragma unroll
        for (int q = 1; q < 6; q++) job += (g >= j.pfx[q]) ? 1 : 0;
        int i4 = g - j.pfx[job];
        cvt_one(j.src[job], j.dst[job], j.Msrc[job], j.Ksrc[job], j.Kdst[job],
                j.rmul[job], j.radd[job], i4);
    }
}

// ---------------- bf16 MFMA GEMM: C[N,M] = A[N,K] @ W[M,K]^T ----------------
// BK=64 (128-B LDS rows), XOR swizzle cb ^= (row&7)<<4 both-sides.
// m97 single-buffer 2-barrier core.
// MODE 0: C fp32 NT. MODE 1: += res. MODE 3: silu-fused.
// MODE 4: rope-fused qkv epilogue; V written TRANSPOSED direct to vt.
template <int MODE, int BM, int BN>
__global__ __launch_bounds__(256) void gemm_bt(const bf16* __restrict__ A,
                                               const bf16* __restrict__ W16,
                                               const float* res, void* Cv,
                                               int N, int M, int K,
                                               const float* __restrict__ st,
                                               const float* __restrict__ ct,
                                               bf16* qp, bf16* kp, bf16* vt) {
    constexpr int MF = BM / 32;
    constexpr int NF = BN / 32;
    constexpr int ACH = BM / 32;
    constexpr int BCH = BN / 32;
    __shared__ __align__(16) bf16 As[BM * 64];
    __shared__ __align__(16) bf16 Bs[BN * 64];

    int t = threadIdx.x;
    int nnt = N / BM;
    int nmt = M / BN;
    int nwg = nmt * nnt;
    int orig = blockIdx.x;
    int q8 = nwg >> 3;
    int wgid = (orig & 7) * q8 + (orig >> 3);   // XCD-chunked, bijective (nwg%8==0)
    int mt, nt;
    if constexpr (BM == 128 && BN == 128) {      // 2m x 16n supertile
        int stile = wgid >> 5, rem = wgid & 31;
        mt = (stile << 1) + (rem & 1);
        nt = rem >> 1;
    } else {                                     // n-fastest
        mt = wgid / nnt;
        nt = wgid - mt * nnt;
    }
    int m0 = mt * BN;
    int n0 = nt * BM;

    int lane = t & 63;
    int wave = t >> 6;
    int wr = (wave >> 1) * (BM / 2);
    int wc = (wave & 1) * (BN / 2);
    int qi = lane & 15;
    int g4 = lane >> 4;

    int arow[ACH], asc[ACH], apos[ACH];
#pragma unroll
    for (int i = 0; i < ACH; i++) {
        int p = (t + i * 256) * 16;
        arow[i] = p >> 7;
        asc[i] = (p & 127) ^ ((arow[i] & 7) << 4);
        apos[i] = p;
    }
    int brow[BCH], bsc[BCH], bpos[BCH];
#pragma unroll
    for (int i = 0; i < BCH; i++) {
        int p = (t + i * 256) * 16;
        brow[i] = p >> 7;
        bsc[i] = (p & 127) ^ ((brow[i] & 7) << 4);
        bpos[i] = p;
    }

    f32x4 acc[MF][NF] = {};

    for (int k0 = 0; k0 < K; k0 += 64) {
        __syncthreads();
#pragma unroll
        for (int i = 0; i < ACH; i++)
            GLOAD16(A + (size_t)(n0 + arow[i]) * K + k0 + (asc[i] >> 1),
                    (char*)As + apos[i]);
#pragma unroll
        for (int i = 0; i < BCH; i++)
            GLOAD16(W16 + (size_t)(m0 + brow[i]) * K + k0 + (bsc[i] >> 1),
                    (char*)Bs + bpos[i]);
        __syncthreads();

#pragma unroll
        for (int h = 0; h < 2; h++) {
            int cb = h * 64 + g4 * 16;
            bf16x8 af[MF], bfr[NF];
#pragma unroll
            for (int m = 0; m < MF; m++) {
                int r = wr + m * 16 + qi;
                af[m] = *(const bf16x8*)((const char*)As + r * 128 + (cb ^ ((r & 7) << 4)));
            }
#pragma unroll
            for (int n = 0; n < NF; n++) {
                int r = wc + n * 16 + qi;
                bfr[n] = *(const bf16x8*)((const char*)Bs + r * 128 + (cb ^ ((r & 7) << 4)));
            }
#pragma unroll
            for (int m = 0; m < MF; m++)
#pragma unroll
                for (int n = 0; n < NF; n++)
                    acc[m][n] = __builtin_amdgcn_mfma_f32_16x16x32_bf16(af[m], bfr[n], acc[m][n], 0, 0, 0);
        }
    }

    int colb = m0 + wc + qi;
    int rowb = n0 + wr + g4 * 4;

    if constexpr (MODE == 0) {
        float* Cf = (float*)Cv;
#pragma unroll
        for (int m = 0; m < MF; m++) {
#pragma unroll
            for (int n = 0; n < NF; n++) {
#pragma unroll
                for (int r = 0; r < 4; r++) {
                    size_t off = (size_t)(rowb + m * 16 + r) * M + (colb + n * 16);
                    __builtin_nontemporal_store(acc[m][n][r], Cf + off);
                }
            }
        }
    } else if constexpr (MODE == 1) {
        float* Cf = (float*)Cv;
#pragma unroll
        for (int m = 0; m < MF; m++) {
#pragma unroll
            for (int n = 0; n < NF; n++) {
#pragma unroll
                for (int r = 0; r < 4; r++) {
                    size_t off = (size_t)(rowb + m * 16 + r) * M + (colb + n * 16);
                    Cf[off] = acc[m][n][r] + res[off];
                }
            }
        }
    } else if constexpr (MODE == 3) {
        bf16* Cb = (bf16*)Cv;
        int M2 = M >> 1;
        bool even = (lane & 1) == 0;
#pragma unroll
        for (int m = 0; m < MF; m++) {
#pragma unroll
            for (int n = 0; n < NF; n++) {
#pragma unroll
                for (int r = 0; r < 4; r++) {
                    float own = acc[m][n][r];
                    float oth = __shfl_xor(own, 1);
                    if (even) {
                        float sv = own / (1.0f + __expf(-own)) * oth;
                        int oc = (colb + n * 16) >> 1;
                        Cb[(size_t)(rowb + m * 16 + r) * M2 + oc] = __float2bfloat16(sv);
                    }
                }
            }
        }
    } else if constexpr (MODE == 4) {
        int h = (m0 + wc) >> 6;
#pragma unroll
        for (int m = 0; m < MF; m++) {
            if (h < 20) {
#pragma unroll
                for (int r = 0; r < 4; r++) {
                    int row = rowb + m * 16 + r;
                    int tt = row & (TT - 1);
                    int b = row >> 10;
#pragma unroll
                    for (int n = 0; n < 2; n++) {
                        int dlo = qi + n * 16;
                        float alo = acc[m][n][r];
                        float ahi = acc[m][n + 2][r];
                        float c = ct[tt * 64 + dlo];
                        float s = st[tt * 64 + dlo];
                        float olo = alo * c - ahi * s;
                        float ohi = ahi * c + alo * s;
                        if (h < 16) {
                            olo *= 0.125f; ohi *= 0.125f;
                            bf16* q = qp + (((size_t)(b * NH + h) * TT + tt) * 64);
                            q[dlo] = __float2bfloat16(olo);
                            q[dlo + 32] = __float2bfloat16(ohi);
                        } else {
                            bf16* kk = kp + (((size_t)(b * KVHN + (h - 16)) * TT + tt) * 64);
                            kk[dlo] = __float2bfloat16(olo);
                            kk[dlo + 32] = __float2bfloat16(ohi);
                        }
                    }
                }
            } else {
                int row0 = rowb + m * 16;
                int tt0 = row0 & (TT - 1);
                int b = row0 >> 10;
                int kvh = h - 20;
#pragma unroll
                for (int n = 0; n < 4; n++) {
                    int d = qi + n * 16;
                    ushort4 o;
                    o.x = f2b(acc[m][n][0]);
                    o.y = f2b(acc[m][n][1]);
                    o.z = f2b(acc[m][n][2]);
                    o.w = f2b(acc[m][n][3]);
                    *(ushort4*)(vt + ((size_t)(b * KVHN + kvh) * 64 + d) * TT + tt0) = o;
                }
            }
        }
    }
}

extern "C" void kernel_launch(void* const* d_in, const int* in_sizes, int n_in,
                              void* d_out, int out_size, void* d_ws, size_t ws_size,
                              hipStream_t stream) {
    const int* idx    = (const int*)d_in[0];
    const float* wte  = (const float*)d_in[1];
    const float* Wq   = (const float*)d_in[2];
    const float* Wkv  = (const float*)d_in[3];
    const float* Wo   = (const float*)d_in[4];
    const float* Wg   = (const float*)d_in[5];
    const float* Wu   = (const float*)d_in[6];
    const float* Wd   = (const float*)d_in[7];
    const float* rms1 = (const float*)d_in[8];
    const float* rms2 = (const float*)d_in[9];
    const float* rmsf = (const float*)d_in[10];
    float* out = (float*)d_out;

    char* ws = (char*)d_ws;
    size_t off = 0;
    float* x = (float*)(ws + off);   off += (size_t)NTOK * DD * 4;
    bf16* xn = (bf16*)(ws + off);    off += (size_t)NTOK * DD * 2;
    float* st = (float*)(ws + off);  off += (size_t)TT * 64 * 4;
    float* ct = (float*)(ws + off);  off += (size_t)TT * 64 * 4;
    bf16* yb = (bf16*)(ws + off);    off += (size_t)NTOK * DD * 2;
    bf16* gb = (bf16*)(ws + off);    off += (size_t)NTOK * IIP * 2;
    bf16* qp = (bf16*)(ws + off);    off += (size_t)NTOK * DD * 2;
    bf16* kp = (bf16*)(ws + off);    off += (size_t)BB * KVHN * TT * 64 * 2;
    bf16* vt = (bf16*)(ws + off);    off += (size_t)BB * KVHN * TT * 64 * 2;
    bf16* Wqkv_buf = (bf16*)(ws + off); off += (size_t)QKVD * DD * 2;
    bf16* Wo_buf = (bf16*)(ws + off);   off += (size_t)DD * DD * 2;
    bf16* Wgu_buf = (bf16*)(ws + off);  off += (size_t)2 * IIP * DD * 2;
    bf16* Wd_buf = (bf16*)(ws + off);   off += (size_t)DD * IIP * 2;
    bf16* wte_bf = (bf16*)(ws + off);   off += (size_t)32000 * DD * 2;

    rope_table_k<<<(TT * 64 + 255) / 256, 256, 0, stream>>>(st, ct);
    embed_k<<<NTOK, 256, 0, stream>>>(idx, wte, x);

    for (int l = 0; l < NL; ++l) {
        CvtJobs j;
        int n4[6];
        j.src[0] = Wq + (size_t)l * DD * DD;   j.dst[0] = Wqkv_buf;
        j.Msrc[0] = DD;  j.Ksrc[0] = DD;  j.Kdst[0] = DD;  n4[0] = DD * DD / 4;
        j.rmul[0] = 1; j.radd[0] = 0;
        j.src[1] = Wkv + (size_t)l * 512 * DD; j.dst[1] = Wqkv_buf + (size_t)DD * DD;
        j.Msrc[1] = 512; j.Ksrc[1] = DD;  j.Kdst[1] = DD;  n4[1] = 512 * DD / 4;
        j.rmul[1] = 1; j.radd[1] = 0;
        j.src[2] = Wo + (size_t)l * DD * DD;   j.dst[2] = Wo_buf;
        j.Msrc[2] = DD;  j.Ksrc[2] = DD;  j.Kdst[2] = DD;  n4[2] = DD * DD / 4;
        j.rmul[2] = 1; j.radd[2] = 0;
        j.src[3] = Wg + (size_t)l * II * DD;   j.dst[3] = Wgu_buf;   // rows 2i
        j.Msrc[3] = II;  j.Ksrc[3] = DD;  j.Kdst[3] = DD;  n4[3] = IIP * DD / 4;
        j.rmul[3] = 2; j.radd[3] = 0;
        j.src[4] = Wu + (size_t)l * II * DD;   j.dst[4] = Wgu_buf;   // rows 2i+1
        j.Msrc[4] = II;  j.Ksrc[4] = DD;  j.Kdst[4] = DD;  n4[4] = IIP * DD / 4;
        j.rmul[4] = 2; j.radd[4] = 1;
        j.src[5] = Wd + (size_t)l * DD * II;   j.dst[5] = Wd_buf;
        j.Msrc[5] = DD;  j.Ksrc[5] = II;  j.Kdst[5] = IIP; n4[5] = DD * IIP / 4;
        j.rmul[5] = 1; j.radd[5] = 0;
        j.pfx[0] = 0;
        for (int q = 0; q < 6; q++) j.pfx[q + 1] = j.pfx[q] + n4[q];
        cvt_fused_k<<<2048, 256, 0, stream>>>(j);

        // --- attention block ---
        rmsnorm_k<<<NTOK, 256, 0, stream>>>(x, rms1 + (size_t)l * DD, xn);
        gemm_bt<4, 64, 128><<<(QKVD / 128) * (NTOK / 64), 256, 0, stream>>>(
            xn, Wqkv_buf, nullptr, nullptr, NTOK, QKVD, DD, st, ct, qp, kp, vt);
        attn_mfma_k<<<512, 256, 0, stream>>>(qp, kp, vt, yb);
        gemm_bt<1, 64, 64><<<(DD / 64) * (NTOK / 64), 256, 0, stream>>>(
            yb, Wo_buf, x, x, NTOK, DD, DD, nullptr, nullptr, nullptr, nullptr, nullptr);
        // --- mlp block ---
        rmsnorm_k<<<NTOK, 256, 0, stream>>>(x, rms2 + (size_t)l * DD, xn);
        gemm_bt<3, 128, 128><<<(2 * IIP / 128) * (NTOK / 128), 256, 0, stream>>>(
            xn, Wgu_buf, nullptr, gb, NTOK, 2 * IIP, DD, nullptr, nullptr, nullptr, nullptr, nullptr);
        gemm_bt<1, 64, 64><<<(DD / 64) * (NTOK / 64), 256, 0, stream>>>(
            gb, Wd_buf, x, x, NTOK, DD, IIP, nullptr, nullptr, nullptr, nullptr, nullptr);
    }

    // --- final norm + tied lm_head (128x64 BK=64 swizzled, n-fastest, NT) ---
    rmsnorm_k<<<NTOK, 256, 0, stream>>>(x, rmsf, xn);
    cvt_pad_k<<<2048, 256, 0, stream>>>(wte, wte_bf, 32000, DD, DD, 32000 * DD / 4);
    gemm_bt<0, 128, 64><<<(32000 / 64) * (NTOK / 128), 256, 0, stream>>>(
        xn, wte_bf, nullptr, out, NTOK, 32000, DD, nullptr, nullptr, nullptr, nullptr, nullptr);
}